// Round 4
// baseline (122.519 us; speedup 1.0000x reference)
//
#include <hip/hip_runtime.h>
#include <math.h>

#define SA 20        // alphabet
#define KDIM 2
#define MDIM 2
#define BDIM 512
#define LDIM 512
#define NRATES 512
#define NPOW 7                     // Qhat^d, d = 0..6
#define MATW (SA * SA)             // 400 floats
#define PWSTRIDE (NPOW * MATW)     // 2800 floats per (m,k)
#define SPLIT 4                    // blocks per (m,b) pair
#define NCH (LDIM * KDIM * SA / 4) // 5120 float4 chunks per pair
#define GCH (NCH / SPLIT)          // 1280 chunks per block
#define GITER (GCH / 256)          // 5 chunks per thread
#define LSLICE (LDIM / SPLIT)      // 128 l-positions per block

__device__ __forceinline__ float softplusf(float x) {
    return fmaxf(x, 0.0f) + log1pf(expf(-fabsf(x)));
}

// C(row-per-lane regs) = A(regs) * B(LDS 20x20 row-major, contiguous 400-float
// block). Same-address float4 reads broadcast, conflict-free.
__device__ __forceinline__ void mmB(float* C, const float* A, const float* Bl) {
    #pragma unroll
    for (int j = 0; j < SA; ++j) C[j] = 0.0f;
    #pragma unroll
    for (int t = 0; t < SA; ++t) {
        const float a = A[t];
        const float4* row = reinterpret_cast<const float4*>(Bl + t * SA);
        #pragma unroll
        for (int q = 0; q < 5; ++q) {
            float4 b = row[q];
            C[4*q+0] = fmaf(a, b.x, C[4*q+0]);
            C[4*q+1] = fmaf(a, b.y, C[4*q+1]);
            C[4*q+2] = fmaf(a, b.z, C[4*q+2]);
            C[4*q+3] = fmaf(a, b.w, C[4*q+3]);
        }
    }
}

__device__ __forceinline__ void stageRow(float* dst, const float* T, int row, bool act) {
    if (act) {
        float4* d4 = reinterpret_cast<float4*>(dst + row * SA);
        #pragma unroll
        for (int q = 0; q < 5; ++q)
            d4[q] = make_float4(T[4*q+0], T[4*q+1], T[4*q+2], T[4*q+3]);
    }
}

__device__ __forceinline__ void writeMat(float* base, const float* T, int row, bool act) {
    if (act) {
        float4* d4 = reinterpret_cast<float4*>(base + row * SA);
        #pragma unroll
        for (int q = 0; q < 5; ++q)
            d4[q] = make_float4(T[4*q+0], T[4*q+1], T[4*q+2], T[4*q+3]);
    }
}

// ---- Kernel 1: build Qhat per (m,k) and its powers d=0..6; 2 blocks x 64 ----
__global__ __launch_bounds__(64) void powers_kernel(
    const float* __restrict__ Ek,
    const float* __restrict__ eqk,
    float*       __restrict__ Pw,      // (4, 7, 400)
    float*       __restrict__ nInf)    // (4,)
{
    __shared__ float sB[KDIM * MATW];

    const int lane = threadIdx.x;
    const int mm   = blockIdx.x;
    const int half = lane >> 5;
    const int row  = lane & 31;
    const bool act = row < SA;
    const int mk   = mm * KDIM + half;
    float* stg = sB + half * MATW;

    // p = softmax(eqk)
    float e = act ? eqk[mk * SA + row] : -INFINITY;
    float mx = e;
    #pragma unroll
    for (int off = 16; off; off >>= 1) mx = fmaxf(mx, __shfl_xor(mx, off, 32));
    float ex = act ? expf(e - mx) : 0.0f;
    float sm = ex;
    #pragma unroll
    for (int off = 16; off; off >>= 1) sm += __shfl_xor(sm, off, 32);
    float p_i = ex / sm;

    // Qhat = normalized rate matrix (row per lane)
    const int r0 = act ? row : 0;
    float Q[SA];
    float dg = 0.0f;
    #pragma unroll
    for (int j = 0; j < SA; ++j) {
        float pj = __shfl(p_i, j, 32);
        float e1 = Ek[(mk * SA + r0) * SA + j];
        float e2 = Ek[(mk * SA + j) * SA + r0];
        float r  = (j == row) ? 0.0f : softplusf(0.5f * (e1 + e2));
        float q  = r * pj;
        Q[j] = q;
        dg  += q;
    }
    float t_ = act ? p_i * dg : 0.0f;
    #pragma unroll
    for (int off = 16; off; off >>= 1) t_ += __shfl_xor(t_, off, 32);
    const float inv = 1.0f / fmaxf(t_, 1e-16f);
    #pragma unroll
    for (int j = 0; j < SA; ++j)
        Q[j] = act ? ((j == row) ? -dg * inv : Q[j] * inv) : 0.0f;

    // nInf = ||Qhat||_inf
    float rn = 0.0f;
    #pragma unroll
    for (int j = 0; j < SA; ++j) rn += fabsf(Q[j]);
    #pragma unroll
    for (int off = 16; off; off >>= 1) rn = fmaxf(rn, __shfl_xor(rn, off, 32));
    if (act && row == 0) nInf[mk] = rn;

    float* base = Pw + (size_t)mk * PWSTRIDE;
    // d = 0: identity
    if (act) {
        float I[SA];
        #pragma unroll
        for (int j = 0; j < SA; ++j) I[j] = (j == row) ? 1.0f : 0.0f;
        writeMat(base + 0 * MATW, I, row, act);
    }
    writeMat(base + 1 * MATW, Q, row, act);

    stageRow(stg, Q, row, act);
    __syncthreads();
    float G2[SA], G3[SA];
    mmB(G2, Q, stg);                    // Q^2
    writeMat(base + 2 * MATW, G2, row, act);
    mmB(G3, G2, stg);                   // Q^3
    writeMat(base + 3 * MATW, G3, row, act);
    __syncthreads();
    stageRow(stg, G2, row, act);
    __syncthreads();
    {
        float G4[SA];
        mmB(G4, G2, stg);               // Q^4 = Q^2 * Q^2
        writeMat(base + 4 * MATW, G4, row, act);
    }
    {
        float G5[SA];
        mmB(G5, G3, stg);               // Q^5 = Q^3 * Q^2
        writeMat(base + 5 * MATW, G5, row, act);
    }
    __syncthreads();
    stageRow(stg, G3, row, act);
    __syncthreads();
    {
        float G6[SA];
        mmB(G6, G3, stg);               // Q^6 = Q^3 * Q^3
        writeMat(base + 6 * MATW, G6, row, act);
    }
}

// ---- Kernel 2: per-pair linear combo of powers (+ rare squarings) + gather --
__global__ __launch_bounds__(256) void combo_gather_kernel(
    const int*   __restrict__ seqg,
    const int*   __restrict__ rateIdx,
    const float* __restrict__ tauk,
    const float* __restrict__ Pw,
    const float* __restrict__ nInf,
    float*       __restrict__ out)
{
    __shared__ float sPw[KDIM * PWSTRIDE];   // 5600 floats = 22.4 KB
    __shared__ float sP[KDIM * MATW];        // 800 floats = 3.2 KB
    __shared__ int   sSeq[LSLICE];           // 128 ints

    const int tid = threadIdx.x;
    const int mb  = blockIdx.x >> 2;         // pair in [0,1024)
    const int qq  = blockIdx.x & 3;          // quarter
    const int mm  = mb >> 9;                 // BDIM = 512

    // stage both k's power tables: 1400 float4, coalesced
    {
        const float4* src = reinterpret_cast<const float4*>(Pw + (size_t)mm * KDIM * PWSTRIDE);
        float4* dst = reinterpret_cast<float4*>(sPw);
        for (int f = tid; f < KDIM * PWSTRIDE / 4; f += 256) dst[f] = src[f];
    }
    // stage this quarter's 128 sequence ints (wave 1, lanes 0..31)
    if (tid >= 64 && tid < 96) {
        reinterpret_cast<int4*>(sSeq)[tid - 64] =
            reinterpret_cast<const int4*>(seqg + (size_t)mb * LDIM)[qq * (LSLICE / 4) + (tid - 64)];
    }
    __syncthreads();

    if (tid < 64) {
        const int lane = tid;
        const int half = lane >> 5;
        const int row  = lane & 31;
        const bool act = row < SA;
        const int r0   = act ? row : 0;

        const float tau = softplusf(tauk[mm * NRATES + rateIdx[mb]]);
        const float n   = nInf[mm * KDIM + half];
        float x0 = tau * n;
        int s = 0;
        if (x0 > 1.0f) s = (int)ceilf(log2f(x0));
        if (s < 0) s = 0;
        if (s > 30) s = 30;
        const float x = tau * exp2f(-(float)s);

        float cf[NPOW];
        cf[0] = 1.0f;
        cf[1] = x;
        cf[2] = cf[1] * x * 0.5f;
        cf[3] = cf[2] * x * (1.0f / 3.0f);
        cf[4] = cf[3] * x * 0.25f;
        cf[5] = cf[4] * x * 0.2f;
        cf[6] = cf[5] * x * (1.0f / 6.0f);

        // T = sum_d cf[d] * Qhat^d  (row r0 per lane)
        float T[SA];
        #pragma unroll
        for (int j = 0; j < SA; ++j) T[j] = (j == row) ? 1.0f : 0.0f;
        const float* pb = sPw + half * PWSTRIDE + r0 * SA;
        #pragma unroll
        for (int d = 1; d < NPOW; ++d) {
            const float c = cf[d];
            const float4* rp = reinterpret_cast<const float4*>(pb + d * MATW);
            #pragma unroll
            for (int q = 0; q < 5; ++q) {
                float4 b = rp[q];
                T[4*q+0] = fmaf(c, b.x, T[4*q+0]);
                T[4*q+1] = fmaf(c, b.y, T[4*q+1]);
                T[4*q+2] = fmaf(c, b.z, T[4*q+2]);
                T[4*q+3] = fmaf(c, b.w, T[4*q+3]);
            }
        }

        // rare squarings: T <- T^2, s times (smax = wave max; predicated keep)
        const int smax = max(s, __shfl_xor(s, 32));
        float* stg = sP + half * MATW;
        for (int it = 0; it < smax; ++it) {
            stageRow(stg, T, row, act);
            float Tn[SA];
            mmB(Tn, T, stg);
            const bool doit = it < s;
            #pragma unroll
            for (int j = 0; j < SA; ++j) T[j] = doit ? Tn[j] : T[j];
        }
        stageRow(stg, T, row, act);      // final P into sP
    }
    __syncthreads();

    // gather + coalesced stream out: out[mb, l, kk, :] = P[kk][seq[l]][:]
    const float4* pv = reinterpret_cast<const float4*>(sP);
    float4* o4 = reinterpret_cast<float4*>(out) + (size_t)mb * NCH;
    const int cb = qq * GCH + tid;
    #pragma unroll
    for (int i = 0; i < GITER; ++i) {
        const int c  = cb + i * 256;
        const int l  = c / 10;
        const int ch = c - l * 10;
        const int kk = (ch >= 5) ? 1 : 0;
        const int c4 = ch - kk * 5;
        const int sq = sSeq[l - qq * LSLICE];
        o4[c] = pv[(kk * SA + sq) * 5 + c4];
    }
}

extern "C" void kernel_launch(void* const* d_in, const int* in_sizes, int n_in,
                              void* d_out, int out_size, void* d_ws, size_t ws_size,
                              hipStream_t stream) {
    const int*   seq  = (const int*)d_in[0];
    const int*   ridx = (const int*)d_in[1];
    const float* tauk = (const float*)d_in[2];
    const float* Ek   = (const float*)d_in[3];
    const float* eqk  = (const float*)d_in[4];
    float* out  = (float*)d_out;
    float* Pw   = (float*)d_ws;                               // 11200 floats
    float* nInf = (float*)d_ws + MDIM * KDIM * PWSTRIDE;      // 4 floats

    powers_kernel<<<MDIM, 64, 0, stream>>>(Ek, eqk, Pw, nInf);
    combo_gather_kernel<<<MDIM * BDIM * SPLIT, 256, 0, stream>>>(
        seq, ridx, tauk, Pw, nInf, out);
}